// Round 1
// 144.790 us; speedup vs baseline: 1.0502x; 1.0502x over previous
//
#include <hip/hip_runtime.h>
#include <math.h>

#define DIN 128
#define DOUT 128
#define EPS 1e-5f
#define CHUNK_SHIFT 11     // 2048 src nodes/chunk -> 2 MB of hb, fits 4 MB per-XCD L2
#define CAPC 32            // per-(node,chunk) bucket cap; deg/chunk ~ Poisson(6.6)

typedef unsigned short ushort_t;
typedef __bf16 bf16x8 __attribute__((ext_vector_type(8)));
typedef float f32x16 __attribute__((ext_vector_type(16)));

__device__ __forceinline__ unsigned int f2bf_u(float f) {
    union { float f; unsigned int i; } v; v.f = f;
    unsigned int x = v.i;
    unsigned int r = x + 0x7fffu + ((x >> 16) & 1u);  // RNE
    return r >> 16;
}
__device__ __forceinline__ ushort_t f2bf(float f) { return (ushort_t)f2bf_u(f); }

// ---------------------------------------------------------------------------
// Kernel 0: prep — swizzle W into global bf16 B-fragment order (32 KB, shared
// by all gemm blocks via L2) AND zero the per-(node,chunk) edge counters.
// ---------------------------------------------------------------------------
__global__ __launch_bounds__(256) void prep_kernel(
    const float* __restrict__ W, uint4* __restrict__ wb,
    int* __restrict__ counts, int total_counts)
{
    int t = blockIdx.x * blockDim.x + threadIdx.x;
    if (t < 2048) {
        int ct = t >> 9, kc = (t >> 6) & 7, l = t & 63;
        int o = ct * 32 + (l & 31);
        int f = kc * 16 + ((l >> 5) << 3);
        const float4* src = (const float4*)(W + o * 128 + f);
        float4 v0 = src[0], v1 = src[1];
        uint4 pk;
        pk.x = f2bf_u(v0.x) | (f2bf_u(v0.y) << 16);
        pk.y = f2bf_u(v0.z) | (f2bf_u(v0.w) << 16);
        pk.z = f2bf_u(v1.x) | (f2bf_u(v1.y) << 16);
        pk.w = f2bf_u(v1.z) | (f2bf_u(v1.w) << 16);
        wb[t] = pk;
    }
    for (int i = t; i < total_counts; i += gridDim.x * blockDim.x) counts[i] = 0;
}

// ---------------------------------------------------------------------------
// Kernel 1: h = GELU(BN(x @ W^T + b)) via bf16 MFMA, + fused bucket-CSR fill.
// Block = 256 threads (4 waves), 16 nodes x 4 batches = 64 rows, grid = 625.
// CSR is now chunked by src >> CHUNK_SHIFT so the gather can cache-block:
// bucket key = dst*nc + chunk(src), CAPC=32 slots each.
// Output hb[n][c][b] bf16, contiguous 16 KB store per block.
// ---------------------------------------------------------------------------
__global__ __launch_bounds__(256, 4) void gemm_bn_gelu_fill(
    const float* __restrict__ x, const uint4* __restrict__ wb,
    const float* __restrict__ bias, const float* __restrict__ gamma,
    const float* __restrict__ beta, const float* __restrict__ mean,
    const float* __restrict__ var, ushort_t* __restrict__ hb,
    const int* __restrict__ ei, const float* __restrict__ norm,
    int* __restrict__ counts, unsigned int* __restrict__ csr,
    int N, int E, int nc)
{
    __shared__ ushort_t XH[8192];      // A-frag order during K-loop; Ho after
    __shared__ float sm_mu[16], sm_sc[16], sm_bt[16];

    const int tid = threadIdx.x;
    const int n0 = blockIdx.x * 16;
    const int w = tid >> 6;
    const int lane = tid & 63;

    // ---- W fragments: direct global load, issued early to overlap ----
    bf16x8 bfr[8];
#pragma unroll
    for (int kc = 0; kc < 8; ++kc)
        bfr[kc] = *(const bf16x8*)(wb + (w * 512 + kc * 64 + lane));

    // ---- fused chunked-CSR fill: 2 edges/thread, loads issued upfront ----
    {
        const int gid = blockIdx.x * blockDim.x + tid;
        const int stride = gridDim.x * blockDim.x;
        for (int e = gid; e < E; e += 2 * stride) {
            int ep = e + stride;
            int has2 = ep < E;
            int dst0 = ei[e];
            int src0 = ei[E + e];
            float nm0 = norm[e];
            int dst1 = 0, src1 = 0;
            float nm1 = 0.f;
            if (has2) { dst1 = ei[ep]; src1 = ei[E + ep]; nm1 = norm[ep]; }
            int b0 = dst0 * nc + (src0 >> CHUNK_SHIFT);
            int slot0 = atomicAdd(&counts[b0], 1);
            if (slot0 < CAPC)
                csr[((size_t)b0 << 5) + slot0] =
                    ((unsigned int)src0 << 16) | f2bf_u(nm0);
            if (has2) {
                int b1 = dst1 * nc + (src1 >> CHUNK_SHIFT);
                int slot1 = atomicAdd(&counts[b1], 1);
                if (slot1 < CAPC)
                    csr[((size_t)b1 << 5) + slot1] =
                        ((unsigned int)src1 << 16) | f2bf_u(nm1);
            }
        }
    }

    // ---- BN params for this block's 16 nodes ----
    if (tid < 16) {
        int n = n0 + tid;
        sm_mu[tid] = mean[n];
        sm_sc[tid] = rsqrtf(var[n] + EPS) * gamma[n];
        sm_bt[tid] = beta[n];
    }

    // ---- stage X in A-fragment order: packed b128 LDS stores ----
#pragma unroll
    for (int it = 0; it < 4; ++it) {
        int tup = tid + it * 256;
        int rt = tup >> 9, kc = (tup >> 6) & 7, l = tup & 63;
        int r = rt * 32 + (l & 31);
        int b = r >> 4, i = r & 15;
        size_t grow = (size_t)b * N + n0 + i;
        int f = kc * 16 + ((l >> 5) << 3);
        const float4* src = (const float4*)(x + grow * 128 + f);
        float4 v0 = src[0], v1 = src[1];
        uint4 pk;
        pk.x = f2bf_u(v0.x) | (f2bf_u(v0.y) << 16);
        pk.y = f2bf_u(v0.z) | (f2bf_u(v0.w) << 16);
        pk.z = f2bf_u(v1.x) | (f2bf_u(v1.y) << 16);
        pk.w = f2bf_u(v1.z) | (f2bf_u(v1.w) << 16);
        *(uint4*)&XH[tup * 8] = pk;
    }
    __syncthreads();

    f32x16 acc0 = {};  // rows 0..31  (batches 0,1)
    f32x16 acc1 = {};  // rows 32..63 (batches 2,3)
#pragma unroll
    for (int kc = 0; kc < 8; ++kc) {
        bf16x8 a0 = *(const bf16x8*)&XH[(kc * 64 + lane) * 8];
        bf16x8 a1 = *(const bf16x8*)&XH[(512 * 8) + (kc * 64 + lane) * 8];
        acc0 = __builtin_amdgcn_mfma_f32_32x32x16_bf16(a0, bfr[kc], acc0, 0, 0, 0);
        acc1 = __builtin_amdgcn_mfma_f32_32x32x16_bf16(a1, bfr[kc], acc1, 0, 0, 0);
    }
    __syncthreads();   // done reading XH; reuse as Ho

    // ---- epilogue: bias + BN + exact GELU; pack 4 batches per (i,c) ----
    // C/D layout: col = lane&31, rowin32 = (reg&3) + 8*(reg>>2) + 4*(lane>>5)
    const int col = w * 32 + (lane & 31);
    const float bias_c = bias[col];
    const int hi4 = (lane >> 5) * 4;
#pragma unroll
    for (int reg = 0; reg < 8; ++reg) {
        int i0 = (reg & 3) + 8 * (reg >> 2) + hi4;
        float mu = sm_mu[i0], sc = sm_sc[i0], bt = sm_bt[i0];
        float vals[4] = { acc0[reg], acc0[reg + 8], acc1[reg], acc1[reg + 8] };
        ushort4 pk;
        {
            float v = vals[0] + bias_c; v = (v - mu) * sc + bt;
            pk.x = f2bf(0.5f * v * (1.0f + erff(v * 0.70710678118654752f)));
        }
        {
            float v = vals[1] + bias_c; v = (v - mu) * sc + bt;
            pk.y = f2bf(0.5f * v * (1.0f + erff(v * 0.70710678118654752f)));
        }
        {
            float v = vals[2] + bias_c; v = (v - mu) * sc + bt;
            pk.z = f2bf(0.5f * v * (1.0f + erff(v * 0.70710678118654752f)));
        }
        {
            float v = vals[3] + bias_c; v = (v - mu) * sc + bt;
            pk.w = f2bf(0.5f * v * (1.0f + erff(v * 0.70710678118654752f)));
        }
        *(ushort4*)&XH[((i0 << 7) + col) << 2] = pk;   // Ho[i0][col][0..3]
    }
    __syncthreads();

    {
        const float4* s = (const float4*)XH;
        float4* d = (float4*)(hb + (size_t)n0 * 512);
#pragma unroll
        for (int i = tid; i < 1024; i += 256) d[i] = s[i];
    }
}

// ---------------------------------------------------------------------------
// Kernel 2: out[b,n,c] = sum_{e in bucket(n)} h[src(e)][c][b] * w(e)
// One WAVE per node (4 nodes / 256-thread block). Lane owns 2 channels x 4
// batches = one contiguous int4 (16B) of hb per edge.
// CACHE-BLOCKED over src chunks: all waves sweep chunks 0..nc-1 in the same
// order; each chunk's hb slice (2 MB) stays resident in the per-XCD L2, so
// the 327 MB of gathered reads become L2 hits instead of L3 misses.
// Per chunk: one masked 8-wide burst (slots >= cnt get meta=0 -> src 0,
// weight +0.0) -> no remainder loop, no csr pre-zeroing needed.
// ---------------------------------------------------------------------------
__device__ __forceinline__ void fma8(float* acc, int4 h, float wgt) {
    union { unsigned int i; float f; } t;
    unsigned int u;
    u = (unsigned int)h.x;
    t.i = u << 16;          acc[0] = fmaf(t.f, wgt, acc[0]);   // c0 b0
    t.i = u & 0xffff0000u;  acc[1] = fmaf(t.f, wgt, acc[1]);   // c0 b1
    u = (unsigned int)h.y;
    t.i = u << 16;          acc[2] = fmaf(t.f, wgt, acc[2]);   // c0 b2
    t.i = u & 0xffff0000u;  acc[3] = fmaf(t.f, wgt, acc[3]);   // c0 b3
    u = (unsigned int)h.z;
    t.i = u << 16;          acc[4] = fmaf(t.f, wgt, acc[4]);   // c1 b0
    t.i = u & 0xffff0000u;  acc[5] = fmaf(t.f, wgt, acc[5]);   // c1 b1
    u = (unsigned int)h.w;
    t.i = u << 16;          acc[6] = fmaf(t.f, wgt, acc[6]);   // c1 b2
    t.i = u & 0xffff0000u;  acc[7] = fmaf(t.f, wgt, acc[7]);   // c1 b3
}

__global__ __launch_bounds__(256) void gather_kernel(
    const ushort_t* __restrict__ hb, const int* __restrict__ counts,
    const unsigned int* __restrict__ csr, float* __restrict__ out,
    int N, int nc)
{
    const int w = threadIdx.x >> 6;
    const int lane = threadIdx.x & 63;
    const int n = blockIdx.x * 4 + w;
    if (n >= N) return;

    float acc[8] = {};
    const int l2 = lane & (CAPC - 1);

    for (int c = 0; c < nc; ++c) {
        int cnt = counts[n * nc + c];
        if (cnt > CAPC) cnt = CAPC;
        if (cnt == 0) continue;
        const unsigned int* bucket = csr + ((size_t)(n * nc + c) << 5);
        unsigned int meta = bucket[l2];          // lanes 32..63 mirror 0..31
        for (int j = 0; j < cnt; j += 8) {
            unsigned int m[8];
#pragma unroll
            for (int k = 0; k < 8; ++k) {
                unsigned int mk =
                    (unsigned int)__builtin_amdgcn_readlane((int)meta, j + k);
                m[k] = (j + k < cnt) ? mk : 0u;  // wave-uniform s_cselect
            }
            int4 h0 = *(const int4*)(hb + (size_t)(m[0] >> 16) * 512 + lane * 8);
            int4 h1 = *(const int4*)(hb + (size_t)(m[1] >> 16) * 512 + lane * 8);
            int4 h2 = *(const int4*)(hb + (size_t)(m[2] >> 16) * 512 + lane * 8);
            int4 h3 = *(const int4*)(hb + (size_t)(m[3] >> 16) * 512 + lane * 8);
            int4 h4 = *(const int4*)(hb + (size_t)(m[4] >> 16) * 512 + lane * 8);
            int4 h5 = *(const int4*)(hb + (size_t)(m[5] >> 16) * 512 + lane * 8);
            int4 h6 = *(const int4*)(hb + (size_t)(m[6] >> 16) * 512 + lane * 8);
            int4 h7 = *(const int4*)(hb + (size_t)(m[7] >> 16) * 512 + lane * 8);
            union { unsigned int i; float f; } wv;
            wv.i = m[0] << 16; fma8(acc, h0, wv.f);
            wv.i = m[1] << 16; fma8(acc, h1, wv.f);
            wv.i = m[2] << 16; fma8(acc, h2, wv.f);
            wv.i = m[3] << 16; fma8(acc, h3, wv.f);
            wv.i = m[4] << 16; fma8(acc, h4, wv.f);
            wv.i = m[5] << 16; fma8(acc, h5, wv.f);
            wv.i = m[6] << 16; fma8(acc, h6, wv.f);
            wv.i = m[7] << 16; fma8(acc, h7, wv.f);
        }
    }

    const size_t bstride = (size_t)N * DOUT;
    float* op = out + (size_t)n * DOUT + lane * 2;
#pragma unroll
    for (int b = 0; b < 4; ++b) {
        float2 v; v.x = acc[b]; v.y = acc[4 + b];
        *(float2*)(op + b * bstride) = v;
    }
}

// ---------------------------------------------------------------------------
extern "C" void kernel_launch(void* const* d_in, const int* in_sizes, int n_in,
                              void* d_out, int out_size, void* d_ws, size_t ws_size,
                              hipStream_t stream)
{
    const float* x     = (const float*)d_in[0];
    const int*   ei    = (const int*)d_in[1];
    const float* norm  = (const float*)d_in[2];
    const float* W_w   = (const float*)d_in[3];
    const float* W_b   = (const float*)d_in[4];
    const float* gamma = (const float*)d_in[5];
    const float* beta  = (const float*)d_in[6];
    const float* mean  = (const float*)d_in[7];
    const float* var   = (const float*)d_in[8];
    float* out = (float*)d_out;

    const int N = in_sizes[5];             // 10000
    const int E = in_sizes[2];             // 320000
    const int nc = (N + (1 << CHUNK_SHIFT) - 1) >> CHUNK_SHIFT;   // 5 chunks

    // Workspace layout (16B-aligned segments)
    ushort_t* hb      = (ushort_t*)d_ws;                  // N*512 bf16 = 10.24 MB
    uint4* wb         = (uint4*)(hb + (size_t)N * 512);   // 2048 uint4 = 32 KB
    int* counts       = (int*)(wb + 2048);                // N*nc ints = 200 KB
    unsigned int* csr = (unsigned int*)(counts + (size_t)N * nc);  // N*nc*32 u32 = 6.4 MB

    int prep_blocks = (N * nc + 255) / 256;   // 196 (covers 2048 W-tuples too)
    prep_kernel<<<prep_blocks, 256, 0, stream>>>(W_w, wb, counts, N * nc);

    int gemm_blocks = N / 16;              // 625, exact
    gemm_bn_gelu_fill<<<gemm_blocks, 256, 0, stream>>>(
        x, wb, W_b, gamma, beta, mean, var, hb, ei, norm, counts, csr, N, E, nc);

    gather_kernel<<<(N + 3) / 4, 256, 0, stream>>>(hb, counts, csr, out, N, nc);
}

// Round 3
// 140.024 us; speedup vs baseline: 1.0859x; 1.0340x over previous
//
#include <hip/hip_runtime.h>
#include <math.h>

#define DIN 128
#define DOUT 128
#define EPS 1e-5f
#define CHUNK_SHIFT 11     // 2048 src nodes/chunk -> 2 MB of hb, fits 4 MB per-XCD L2
#define CAPC 32            // per-(node,chunk) bucket cap; deg/chunk ~ Poisson(6.6)

typedef unsigned short ushort_t;
typedef __bf16 bf16x8 __attribute__((ext_vector_type(8)));
typedef float f32x16 __attribute__((ext_vector_type(16)));

__device__ __forceinline__ unsigned int f2bf_u(float f) {
    union { float f; unsigned int i; } v; v.f = f;
    unsigned int x = v.i;
    unsigned int r = x + 0x7fffu + ((x >> 16) & 1u);  // RNE
    return r >> 16;
}
__device__ __forceinline__ ushort_t f2bf(float f) { return (ushort_t)f2bf_u(f); }

// Exact-erf GELU via Abramowitz-Stegun 7.1.26 (|erf err| <= 1.5e-7, far below
// bf16 rounding). ~15 VALU vs ~30 for libm erff.
__device__ __forceinline__ float gelu_exact(float v) {
    float ax = fabsf(v) * 0.70710678118654752f;          // |v|/sqrt(2)
    float t  = __builtin_amdgcn_rcpf(fmaf(0.3275911f, ax, 1.0f));
    float p  = fmaf(fmaf(fmaf(fmaf(1.061405429f, t, -1.453152027f),
                              t, 1.421413741f),
                         t, -0.284496736f),
                    t, 0.254829592f) * t;
    float e  = __builtin_amdgcn_exp2f(ax * ax * -1.4426950408889634f);
    float erf_ax = fmaf(-p, e, 1.0f);
    float erfv = (v < 0.0f) ? -erf_ax : erf_ax;
    return 0.5f * v * (1.0f + erfv);
}

// ---------------------------------------------------------------------------
// Kernel 0: prep — swizzle W into global bf16 B-fragment order (32 KB, shared
// by all gemm blocks via L2) AND zero the per-(node,chunk) edge counters.
// ---------------------------------------------------------------------------
__global__ __launch_bounds__(256) void prep_kernel(
    const float* __restrict__ W, uint4* __restrict__ wb,
    int* __restrict__ counts, int total_counts)
{
    int t = blockIdx.x * blockDim.x + threadIdx.x;
    if (t < 2048) {
        int ct = t >> 9, kc = (t >> 6) & 7, l = t & 63;
        int o = ct * 32 + (l & 31);
        int f = kc * 16 + ((l >> 5) << 3);
        const float4* src = (const float4*)(W + o * 128 + f);
        float4 v0 = src[0], v1 = src[1];
        uint4 pk;
        pk.x = f2bf_u(v0.x) | (f2bf_u(v0.y) << 16);
        pk.y = f2bf_u(v0.z) | (f2bf_u(v0.w) << 16);
        pk.z = f2bf_u(v1.x) | (f2bf_u(v1.y) << 16);
        pk.w = f2bf_u(v1.z) | (f2bf_u(v1.w) << 16);
        wb[t] = pk;
    }
    for (int i = t; i < total_counts; i += gridDim.x * blockDim.x) counts[i] = 0;
}

// ---------------------------------------------------------------------------
// Kernel 1: h = GELU(BN(x @ W^T + b)) via bf16 MFMA, + fused bucket-CSR fill.
// Block = 256 threads (4 waves), 16 nodes x 4 batches = 64 rows, grid = 625.
// CSR chunked by src >> CHUNK_SHIFT: bucket key = dst*nc + chunk(src),
// CAPC=32 slots each. Output hb[n][c][b] bf16, contiguous 16 KB per block.
// ---------------------------------------------------------------------------
__global__ __launch_bounds__(256, 4) void gemm_bn_gelu_fill(
    const float* __restrict__ x, const uint4* __restrict__ wb,
    const float* __restrict__ bias, const float* __restrict__ gamma,
    const float* __restrict__ beta, const float* __restrict__ mean,
    const float* __restrict__ var, ushort_t* __restrict__ hb,
    const int* __restrict__ ei, const float* __restrict__ norm,
    int* __restrict__ counts, unsigned int* __restrict__ csr,
    int N, int E, int nc)
{
    __shared__ ushort_t XH[8192];      // A-frag order during K-loop; Ho after
    __shared__ float sm_mu[16], sm_sc[16], sm_bt[16];

    const int tid = threadIdx.x;
    const int n0 = blockIdx.x * 16;
    const int w = tid >> 6;
    const int lane = tid & 63;

    // ---- W fragments: direct global load, issued early to overlap ----
    bf16x8 bfr[8];
#pragma unroll
    for (int kc = 0; kc < 8; ++kc)
        bfr[kc] = *(const bf16x8*)(wb + (w * 512 + kc * 64 + lane));

    // ---- fused chunked-CSR fill: 2 edges/thread, loads issued upfront ----
    {
        const int gid = blockIdx.x * blockDim.x + tid;
        const int stride = gridDim.x * blockDim.x;
        for (int e = gid; e < E; e += 2 * stride) {
            int ep = e + stride;
            int has2 = ep < E;
            int dst0 = ei[e];
            int src0 = ei[E + e];
            float nm0 = norm[e];
            int dst1 = 0, src1 = 0;
            float nm1 = 0.f;
            if (has2) { dst1 = ei[ep]; src1 = ei[E + ep]; nm1 = norm[ep]; }
            int b0 = dst0 * nc + (src0 >> CHUNK_SHIFT);
            int slot0 = atomicAdd(&counts[b0], 1);
            if (slot0 < CAPC)
                csr[((size_t)b0 << 5) + slot0] =
                    ((unsigned int)src0 << 16) | f2bf_u(nm0);
            if (has2) {
                int b1 = dst1 * nc + (src1 >> CHUNK_SHIFT);
                int slot1 = atomicAdd(&counts[b1], 1);
                if (slot1 < CAPC)
                    csr[((size_t)b1 << 5) + slot1] =
                        ((unsigned int)src1 << 16) | f2bf_u(nm1);
            }
        }
    }

    // ---- BN params for this block's 16 nodes ----
    if (tid < 16) {
        int n = n0 + tid;
        sm_mu[tid] = mean[n];
        sm_sc[tid] = rsqrtf(var[n] + EPS) * gamma[n];
        sm_bt[tid] = beta[n];
    }

    // ---- stage X in A-fragment order: packed b128 LDS stores ----
#pragma unroll
    for (int it = 0; it < 4; ++it) {
        int tup = tid + it * 256;
        int rt = tup >> 9, kc = (tup >> 6) & 7, l = tup & 63;
        int r = rt * 32 + (l & 31);
        int b = r >> 4, i = r & 15;
        size_t grow = (size_t)b * N + n0 + i;
        int f = kc * 16 + ((l >> 5) << 3);
        const float4* src = (const float4*)(x + grow * 128 + f);
        float4 v0 = src[0], v1 = src[1];
        uint4 pk;
        pk.x = f2bf_u(v0.x) | (f2bf_u(v0.y) << 16);
        pk.y = f2bf_u(v0.z) | (f2bf_u(v0.w) << 16);
        pk.z = f2bf_u(v1.x) | (f2bf_u(v1.y) << 16);
        pk.w = f2bf_u(v1.z) | (f2bf_u(v1.w) << 16);
        *(uint4*)&XH[tup * 8] = pk;
    }
    __syncthreads();

    f32x16 acc0 = {};  // rows 0..31  (batches 0,1)
    f32x16 acc1 = {};  // rows 32..63 (batches 2,3)
#pragma unroll
    for (int kc = 0; kc < 8; ++kc) {
        bf16x8 a0 = *(const bf16x8*)&XH[(kc * 64 + lane) * 8];
        bf16x8 a1 = *(const bf16x8*)&XH[(512 * 8) + (kc * 64 + lane) * 8];
        acc0 = __builtin_amdgcn_mfma_f32_32x32x16_bf16(a0, bfr[kc], acc0, 0, 0, 0);
        acc1 = __builtin_amdgcn_mfma_f32_32x32x16_bf16(a1, bfr[kc], acc1, 0, 0, 0);
    }
    __syncthreads();   // done reading XH; reuse as Ho

    // ---- epilogue: bias + BN + fast exact GELU; pack 4 batches per (i,c) ----
    // C/D layout: col = lane&31, rowin32 = (reg&3) + 8*(reg>>2) + 4*(lane>>5)
    const int col = w * 32 + (lane & 31);
    const float bias_c = bias[col];
    const int hi4 = (lane >> 5) * 4;
#pragma unroll
    for (int reg = 0; reg < 8; ++reg) {
        int i0 = (reg & 3) + 8 * (reg >> 2) + hi4;
        float mu = sm_mu[i0], sc = sm_sc[i0], bt = sm_bt[i0];
        float vals[4] = { acc0[reg], acc0[reg + 8], acc1[reg], acc1[reg + 8] };
        ushort4 pk;
        { float v = (vals[0] + bias_c - mu) * sc + bt; pk.x = f2bf(gelu_exact(v)); }
        { float v = (vals[1] + bias_c - mu) * sc + bt; pk.y = f2bf(gelu_exact(v)); }
        { float v = (vals[2] + bias_c - mu) * sc + bt; pk.z = f2bf(gelu_exact(v)); }
        { float v = (vals[3] + bias_c - mu) * sc + bt; pk.w = f2bf(gelu_exact(v)); }
        *(ushort4*)&XH[((i0 << 7) + col) << 2] = pk;   // Ho[i0][col][0..3]
    }
    __syncthreads();

    {
        const float4* s = (const float4*)XH;
        float4* d = (float4*)(hb + (size_t)n0 * 512);
#pragma unroll
        for (int i = tid; i < 1024; i += 256) d[i] = s[i];
    }
}

// ---------------------------------------------------------------------------
// Kernel 2: out[b,n,c] = sum_{e in bucket(n)} h[src(e)][c][b] * w(e)
// TWO nodes per wave -> 5000 waves total (~20 waves/CU): the ENTIRE grid is
// one co-resident generation, so all waves sweep chunks 0..nc-1 in lock-step
// and each per-XCD L2 holds exactly the live 2 MB hb chunk. out writes happen
// only after the sweep (no mid-sweep L2 pollution). Per chunk per node: one
// masked 8-wide burst chain (slots >= cnt get meta=0 -> src 0, weight +0.0).
// ---------------------------------------------------------------------------
__device__ __forceinline__ void fma8(float* acc, int4 h, float wgt) {
    union { unsigned int i; float f; } t;
    unsigned int u;
    u = (unsigned int)h.x;
    t.i = u << 16;          acc[0] = fmaf(t.f, wgt, acc[0]);   // c0 b0
    t.i = u & 0xffff0000u;  acc[1] = fmaf(t.f, wgt, acc[1]);   // c0 b1
    u = (unsigned int)h.y;
    t.i = u << 16;          acc[2] = fmaf(t.f, wgt, acc[2]);   // c0 b2
    t.i = u & 0xffff0000u;  acc[3] = fmaf(t.f, wgt, acc[3]);   // c0 b3
    u = (unsigned int)h.z;
    t.i = u << 16;          acc[4] = fmaf(t.f, wgt, acc[4]);   // c1 b0
    t.i = u & 0xffff0000u;  acc[5] = fmaf(t.f, wgt, acc[5]);   // c1 b1
    u = (unsigned int)h.w;
    t.i = u << 16;          acc[6] = fmaf(t.f, wgt, acc[6]);   // c1 b2
    t.i = u & 0xffff0000u;  acc[7] = fmaf(t.f, wgt, acc[7]);   // c1 b3
}

__device__ __forceinline__ void burst8(const ushort_t* __restrict__ hb,
                                       unsigned int meta, int j, int cnt,
                                       int lane, float* acc)
{
    unsigned int m[8];
#pragma unroll
    for (int k = 0; k < 8; ++k) {
        unsigned int mk =
            (unsigned int)__builtin_amdgcn_readlane((int)meta, j + k);
        m[k] = (j + k < cnt) ? mk : 0u;   // wave-uniform s_cselect
    }
    int4 h0 = *(const int4*)(hb + (size_t)(m[0] >> 16) * 512 + lane * 8);
    int4 h1 = *(const int4*)(hb + (size_t)(m[1] >> 16) * 512 + lane * 8);
    int4 h2 = *(const int4*)(hb + (size_t)(m[2] >> 16) * 512 + lane * 8);
    int4 h3 = *(const int4*)(hb + (size_t)(m[3] >> 16) * 512 + lane * 8);
    int4 h4 = *(const int4*)(hb + (size_t)(m[4] >> 16) * 512 + lane * 8);
    int4 h5 = *(const int4*)(hb + (size_t)(m[5] >> 16) * 512 + lane * 8);
    int4 h6 = *(const int4*)(hb + (size_t)(m[6] >> 16) * 512 + lane * 8);
    int4 h7 = *(const int4*)(hb + (size_t)(m[7] >> 16) * 512 + lane * 8);
    union { unsigned int i; float f; } wv;
    wv.i = m[0] << 16; fma8(acc, h0, wv.f);
    wv.i = m[1] << 16; fma8(acc, h1, wv.f);
    wv.i = m[2] << 16; fma8(acc, h2, wv.f);
    wv.i = m[3] << 16; fma8(acc, h3, wv.f);
    wv.i = m[4] << 16; fma8(acc, h4, wv.f);
    wv.i = m[5] << 16; fma8(acc, h5, wv.f);
    wv.i = m[6] << 16; fma8(acc, h6, wv.f);
    wv.i = m[7] << 16; fma8(acc, h7, wv.f);
}

__global__ __launch_bounds__(256, 5) void gather_kernel(
    const ushort_t* __restrict__ hb, const int* __restrict__ counts,
    const unsigned int* __restrict__ csr, float* __restrict__ out,
    int N, int nc)
{
    const int w = threadIdx.x >> 6;
    const int lane = threadIdx.x & 63;
    const int na = blockIdx.x * 8 + w * 2;     // wave owns nodes na, na+1
    if (na >= N) return;
    const int nb = na + 1;
    const bool hasB = (nb < N);

    float accA[8] = {}, accB[8] = {};
    const int l2 = lane & (CAPC - 1);

    for (int c = 0; c < nc; ++c) {
        const int ia = na * nc + c;
        const int ib = ia + nc;                // nb*nc + c
        int cntA = counts[ia];
        int cntB = hasB ? counts[ib] : 0;
        unsigned int metaA = csr[((size_t)ia << 5) + l2];
        unsigned int metaB = hasB ? csr[((size_t)ib << 5) + l2] : 0u;
        if (cntA > CAPC) cntA = CAPC;
        if (cntB > CAPC) cntB = CAPC;
        for (int j = 0; j < cntA; j += 8) burst8(hb, metaA, j, cntA, lane, accA);
        for (int j = 0; j < cntB; j += 8) burst8(hb, metaB, j, cntB, lane, accB);
    }

    const size_t bstride = (size_t)N * DOUT;
    float* opA = out + (size_t)na * DOUT + lane * 2;
#pragma unroll
    for (int b = 0; b < 4; ++b) {
        float2 v; v.x = accA[b]; v.y = accA[4 + b];
        *(float2*)(opA + b * bstride) = v;
    }
    if (hasB) {
        float* opB = out + (size_t)nb * DOUT + lane * 2;
#pragma unroll
        for (int b = 0; b < 4; ++b) {
            float2 v; v.x = accB[b]; v.y = accB[4 + b];
            *(float2*)(opB + b * bstride) = v;
        }
    }
}

// ---------------------------------------------------------------------------
extern "C" void kernel_launch(void* const* d_in, const int* in_sizes, int n_in,
                              void* d_out, int out_size, void* d_ws, size_t ws_size,
                              hipStream_t stream)
{
    const float* x     = (const float*)d_in[0];
    const int*   ei    = (const int*)d_in[1];
    const float* norm  = (const float*)d_in[2];
    const float* W_w   = (const float*)d_in[3];
    const float* W_b   = (const float*)d_in[4];
    const float* gamma = (const float*)d_in[5];
    const float* beta  = (const float*)d_in[6];
    const float* mean  = (const float*)d_in[7];
    const float* var   = (const float*)d_in[8];
    float* out = (float*)d_out;

    const int N = in_sizes[5];             // 10000
    const int E = in_sizes[2];             // 320000
    const int nc = (N + (1 << CHUNK_SHIFT) - 1) >> CHUNK_SHIFT;   // 5 chunks

    // Workspace layout (16B-aligned segments)
    ushort_t* hb      = (ushort_t*)d_ws;                  // N*512 bf16 = 10.24 MB
    uint4* wb         = (uint4*)(hb + (size_t)N * 512);   // 2048 uint4 = 32 KB
    int* counts       = (int*)(wb + 2048);                // N*nc ints = 200 KB
    unsigned int* csr = (unsigned int*)(counts + (size_t)N * nc);  // N*nc*32 u32 = 6.4 MB

    int prep_blocks = (N * nc + 255) / 256;   // 196 (covers 2048 W-tuples too)
    prep_kernel<<<prep_blocks, 256, 0, stream>>>(W_w, wb, counts, N * nc);

    int gemm_blocks = N / 16;              // 625, exact
    gemm_bn_gelu_fill<<<gemm_blocks, 256, 0, stream>>>(
        x, wb, W_b, gamma, beta, mean, var, hb, ei, norm, counts, csr, N, E, nc);

    gather_kernel<<<(N + 7) / 8, 256, 0, stream>>>(hb, counts, csr, out, N, nc);
}

// Round 4
// 138.896 us; speedup vs baseline: 1.0947x; 1.0081x over previous
//
#include <hip/hip_runtime.h>
#include <math.h>

#define DIN 128
#define DOUT 128
#define EPS 1e-5f
#define CHUNK_SHIFT 11     // 2048 src nodes/chunk -> 2 MB of hb, fits 4 MB per-XCD L2
#define CAPC 32            // per-(node,chunk) bucket cap; deg/chunk ~ Poisson(6.6)

typedef unsigned short ushort_t;
typedef __bf16 bf16x8 __attribute__((ext_vector_type(8)));
typedef float f32x16 __attribute__((ext_vector_type(16)));

__device__ __forceinline__ unsigned int f2bf_u(float f) {
    union { float f; unsigned int i; } v; v.f = f;
    unsigned int x = v.i;
    unsigned int r = x + 0x7fffu + ((x >> 16) & 1u);  // RNE
    return r >> 16;
}
__device__ __forceinline__ ushort_t f2bf(float f) { return (ushort_t)f2bf_u(f); }

// Exact-erf GELU via Abramowitz-Stegun 7.1.26 (|erf err| <= 1.5e-7, far below
// bf16 rounding). ~15 VALU vs ~30 for libm erff.
__device__ __forceinline__ float gelu_exact(float v) {
    float ax = fabsf(v) * 0.70710678118654752f;          // |v|/sqrt(2)
    float t  = __builtin_amdgcn_rcpf(fmaf(0.3275911f, ax, 1.0f));
    float p  = fmaf(fmaf(fmaf(fmaf(1.061405429f, t, -1.453152027f),
                              t, 1.421413741f),
                         t, -0.284496736f),
                    t, 0.254829592f) * t;
    float e  = __builtin_amdgcn_exp2f(ax * ax * -1.4426950408889634f);
    float erf_ax = fmaf(-p, e, 1.0f);
    float erfv = (v < 0.0f) ? -erf_ax : erf_ax;
    return 0.5f * v * (1.0f + erfv);
}

// ---------------------------------------------------------------------------
// Kernel 0: prep — swizzle W into global bf16 B-fragment order (32 KB, shared
// by all gemm blocks via L2) AND zero the per-(node,chunk) edge counters.
// ---------------------------------------------------------------------------
__global__ __launch_bounds__(256) void prep_kernel(
    const float* __restrict__ W, uint4* __restrict__ wb,
    int* __restrict__ counts, int total_counts)
{
    int t = blockIdx.x * blockDim.x + threadIdx.x;
    if (t < 2048) {
        int ct = t >> 9, kc = (t >> 6) & 7, l = t & 63;
        int o = ct * 32 + (l & 31);
        int f = kc * 16 + ((l >> 5) << 3);
        const float4* src = (const float4*)(W + o * 128 + f);
        float4 v0 = src[0], v1 = src[1];
        uint4 pk;
        pk.x = f2bf_u(v0.x) | (f2bf_u(v0.y) << 16);
        pk.y = f2bf_u(v0.z) | (f2bf_u(v0.w) << 16);
        pk.z = f2bf_u(v1.x) | (f2bf_u(v1.y) << 16);
        pk.w = f2bf_u(v1.z) | (f2bf_u(v1.w) << 16);
        wb[t] = pk;
    }
    for (int i = t; i < total_counts; i += gridDim.x * blockDim.x) counts[i] = 0;
}

// ---------------------------------------------------------------------------
// Kernel 1: h = GELU(BN(x @ W^T + b)) via bf16 MFMA, + fused bucket-CSR fill.
// T14 async-stage split: issue all X global loads into registers FIRST, run
// the fill phase (two dependent device-atomic round trips hide the X-load
// latency), then pack -> LDS. launch_bounds(256,3): grid is 2.44 blocks/CU,
// 3/CU keeps full residency while giving the +32 prefetch VGPRs headroom.
// ---------------------------------------------------------------------------
__global__ __launch_bounds__(256, 3) void gemm_bn_gelu_fill(
    const float* __restrict__ x, const uint4* __restrict__ wb,
    const float* __restrict__ bias, const float* __restrict__ gamma,
    const float* __restrict__ beta, const float* __restrict__ mean,
    const float* __restrict__ var, ushort_t* __restrict__ hb,
    const int* __restrict__ ei, const float* __restrict__ norm,
    int* __restrict__ counts, unsigned int* __restrict__ csr,
    int N, int E, int nc)
{
    __shared__ ushort_t XH[8192];      // A-frag order during K-loop; Ho after
    __shared__ float sm_mu[16], sm_sc[16], sm_bt[16];

    const int tid = threadIdx.x;
    const int n0 = blockIdx.x * 16;
    const int w = tid >> 6;
    const int lane = tid & 63;

    // ---- X staging loads: issue EARLY into registers (land under fill) ----
    float4 xv[8];
#pragma unroll
    for (int it = 0; it < 4; ++it) {
        int tup = tid + it * 256;
        int rt = tup >> 9, kc = (tup >> 6) & 7, l = tup & 63;
        int r = rt * 32 + (l & 31);
        int b = r >> 4, i = r & 15;
        size_t grow = (size_t)b * N + n0 + i;
        int f = kc * 16 + ((l >> 5) << 3);
        const float4* src = (const float4*)(x + grow * 128 + f);
        xv[2 * it]     = src[0];
        xv[2 * it + 1] = src[1];
    }

    // ---- W fragments: direct global load, issued early to overlap ----
    bf16x8 bfr[8];
#pragma unroll
    for (int kc = 0; kc < 8; ++kc)
        bfr[kc] = *(const bf16x8*)(wb + (w * 512 + kc * 64 + lane));

    // ---- BN params for this block's 16 nodes ----
    if (tid < 16) {
        int n = n0 + tid;
        sm_mu[tid] = mean[n];
        sm_sc[tid] = rsqrtf(var[n] + EPS) * gamma[n];
        sm_bt[tid] = beta[n];
    }

    // ---- fused chunked-CSR fill: 2 edges/thread, loads issued upfront ----
    {
        const int gid = blockIdx.x * blockDim.x + tid;
        const int stride = gridDim.x * blockDim.x;
        for (int e = gid; e < E; e += 2 * stride) {
            int ep = e + stride;
            int has2 = ep < E;
            int dst0 = ei[e];
            int src0 = ei[E + e];
            float nm0 = norm[e];
            int dst1 = 0, src1 = 0;
            float nm1 = 0.f;
            if (has2) { dst1 = ei[ep]; src1 = ei[E + ep]; nm1 = norm[ep]; }
            int b0 = dst0 * nc + (src0 >> CHUNK_SHIFT);
            int slot0 = atomicAdd(&counts[b0], 1);
            if (slot0 < CAPC)
                csr[((size_t)b0 << 5) + slot0] =
                    ((unsigned int)src0 << 16) | f2bf_u(nm0);
            if (has2) {
                int b1 = dst1 * nc + (src1 >> CHUNK_SHIFT);
                int slot1 = atomicAdd(&counts[b1], 1);
                if (slot1 < CAPC)
                    csr[((size_t)b1 << 5) + slot1] =
                        ((unsigned int)src1 << 16) | f2bf_u(nm1);
            }
        }
    }

    // ---- pack prefetched X into LDS (A-fragment order, b128 stores) ----
#pragma unroll
    for (int it = 0; it < 4; ++it) {
        int tup = tid + it * 256;
        float4 v0 = xv[2 * it], v1 = xv[2 * it + 1];
        uint4 pk;
        pk.x = f2bf_u(v0.x) | (f2bf_u(v0.y) << 16);
        pk.y = f2bf_u(v0.z) | (f2bf_u(v0.w) << 16);
        pk.z = f2bf_u(v1.x) | (f2bf_u(v1.y) << 16);
        pk.w = f2bf_u(v1.z) | (f2bf_u(v1.w) << 16);
        *(uint4*)&XH[tup * 8] = pk;
    }
    __syncthreads();

    f32x16 acc0 = {};  // rows 0..31  (batches 0,1)
    f32x16 acc1 = {};  // rows 32..63 (batches 2,3)
#pragma unroll
    for (int kc = 0; kc < 8; ++kc) {
        bf16x8 a0 = *(const bf16x8*)&XH[(kc * 64 + lane) * 8];
        bf16x8 a1 = *(const bf16x8*)&XH[(512 * 8) + (kc * 64 + lane) * 8];
        acc0 = __builtin_amdgcn_mfma_f32_32x32x16_bf16(a0, bfr[kc], acc0, 0, 0, 0);
        acc1 = __builtin_amdgcn_mfma_f32_32x32x16_bf16(a1, bfr[kc], acc1, 0, 0, 0);
    }
    __syncthreads();   // done reading XH; reuse as Ho

    // ---- epilogue: bias + BN + fast exact GELU; pack 4 batches per (i,c) ----
    // C/D layout: col = lane&31, rowin32 = (reg&3) + 8*(reg>>2) + 4*(lane>>5)
    const int col = w * 32 + (lane & 31);
    const float bias_c = bias[col];
    const int hi4 = (lane >> 5) * 4;
#pragma unroll
    for (int reg = 0; reg < 8; ++reg) {
        int i0 = (reg & 3) + 8 * (reg >> 2) + hi4;
        float mu = sm_mu[i0], sc = sm_sc[i0], bt = sm_bt[i0];
        float vals[4] = { acc0[reg], acc0[reg + 8], acc1[reg], acc1[reg + 8] };
        ushort4 pk;
        { float v = (vals[0] + bias_c - mu) * sc + bt; pk.x = f2bf(gelu_exact(v)); }
        { float v = (vals[1] + bias_c - mu) * sc + bt; pk.y = f2bf(gelu_exact(v)); }
        { float v = (vals[2] + bias_c - mu) * sc + bt; pk.z = f2bf(gelu_exact(v)); }
        { float v = (vals[3] + bias_c - mu) * sc + bt; pk.w = f2bf(gelu_exact(v)); }
        *(ushort4*)&XH[((i0 << 7) + col) << 2] = pk;   // Ho[i0][col][0..3]
    }
    __syncthreads();

    {
        const float4* s = (const float4*)XH;
        float4* d = (float4*)(hb + (size_t)n0 * 512);
#pragma unroll
        for (int i = tid; i < 1024; i += 256) d[i] = s[i];
    }
}

// ---------------------------------------------------------------------------
// Kernel 2: out[b,n,c] = sum_{e in bucket(n)} h[src(e)][c][b] * w(e)
// FOUR nodes per wave -> 625 blocks (2500 waves, 2.44 blocks/CU): fully
// co-resident at 3 blocks/CU, so all waves sweep chunks 0..nc-1 in lock-step
// and each per-XCD L2 holds exactly the live 2 MB hb chunk. Per chunk the
// wave processes its nodes in PAIRS with dual 8-bursts -> 16 loads in flight
// (2x the MLP of the serial version) and 4x-pooled degree variance.
// Masked slots get meta=0 -> src 0 (L1-hot row), weight +0.0.
// ---------------------------------------------------------------------------
__device__ __forceinline__ void fma8(float* acc, int4 h, float wgt) {
    union { unsigned int i; float f; } t;
    unsigned int u;
    u = (unsigned int)h.x;
    t.i = u << 16;          acc[0] = fmaf(t.f, wgt, acc[0]);   // c0 b0
    t.i = u & 0xffff0000u;  acc[1] = fmaf(t.f, wgt, acc[1]);   // c0 b1
    u = (unsigned int)h.y;
    t.i = u << 16;          acc[2] = fmaf(t.f, wgt, acc[2]);   // c0 b2
    t.i = u & 0xffff0000u;  acc[3] = fmaf(t.f, wgt, acc[3]);   // c0 b3
    u = (unsigned int)h.z;
    t.i = u << 16;          acc[4] = fmaf(t.f, wgt, acc[4]);   // c1 b0
    t.i = u & 0xffff0000u;  acc[5] = fmaf(t.f, wgt, acc[5]);   // c1 b1
    u = (unsigned int)h.w;
    t.i = u << 16;          acc[6] = fmaf(t.f, wgt, acc[6]);   // c1 b2
    t.i = u & 0xffff0000u;  acc[7] = fmaf(t.f, wgt, acc[7]);   // c1 b3
}

__device__ __forceinline__ void burst8(const ushort_t* __restrict__ hbp,
                                       unsigned int meta, int j, int cnt,
                                       int lane, float* acc)
{
    unsigned int m[8];
#pragma unroll
    for (int k = 0; k < 8; ++k) {
        unsigned int mk =
            (unsigned int)__builtin_amdgcn_readlane((int)meta, j + k);
        m[k] = (j + k < cnt) ? mk : 0u;   // wave-uniform s_cselect
    }
    int4 h0 = *(const int4*)(hbp + (size_t)(m[0] >> 16) * 512 + lane * 8);
    int4 h1 = *(const int4*)(hbp + (size_t)(m[1] >> 16) * 512 + lane * 8);
    int4 h2 = *(const int4*)(hbp + (size_t)(m[2] >> 16) * 512 + lane * 8);
    int4 h3 = *(const int4*)(hbp + (size_t)(m[3] >> 16) * 512 + lane * 8);
    int4 h4 = *(const int4*)(hbp + (size_t)(m[4] >> 16) * 512 + lane * 8);
    int4 h5 = *(const int4*)(hbp + (size_t)(m[5] >> 16) * 512 + lane * 8);
    int4 h6 = *(const int4*)(hbp + (size_t)(m[6] >> 16) * 512 + lane * 8);
    int4 h7 = *(const int4*)(hbp + (size_t)(m[7] >> 16) * 512 + lane * 8);
    union { unsigned int i; float f; } wv;
    wv.i = m[0] << 16; fma8(acc, h0, wv.f);
    wv.i = m[1] << 16; fma8(acc, h1, wv.f);
    wv.i = m[2] << 16; fma8(acc, h2, wv.f);
    wv.i = m[3] << 16; fma8(acc, h3, wv.f);
    wv.i = m[4] << 16; fma8(acc, h4, wv.f);
    wv.i = m[5] << 16; fma8(acc, h5, wv.f);
    wv.i = m[6] << 16; fma8(acc, h6, wv.f);
    wv.i = m[7] << 16; fma8(acc, h7, wv.f);
}

__device__ __forceinline__ void dual8(const ushort_t* __restrict__ hbp,
                                      unsigned int mA, int jA, int cA, float* aA,
                                      unsigned int mB, int jB, int cB, float* aB,
                                      int lane)
{
    unsigned int a[8], b[8];
#pragma unroll
    for (int k = 0; k < 8; ++k) {
        unsigned int v =
            (unsigned int)__builtin_amdgcn_readlane((int)mA, jA + k);
        a[k] = (jA + k < cA) ? v : 0u;
    }
#pragma unroll
    for (int k = 0; k < 8; ++k) {
        unsigned int v =
            (unsigned int)__builtin_amdgcn_readlane((int)mB, jB + k);
        b[k] = (jB + k < cB) ? v : 0u;
    }
    int4 hA0 = *(const int4*)(hbp + (size_t)(a[0] >> 16) * 512 + lane * 8);
    int4 hA1 = *(const int4*)(hbp + (size_t)(a[1] >> 16) * 512 + lane * 8);
    int4 hA2 = *(const int4*)(hbp + (size_t)(a[2] >> 16) * 512 + lane * 8);
    int4 hA3 = *(const int4*)(hbp + (size_t)(a[3] >> 16) * 512 + lane * 8);
    int4 hA4 = *(const int4*)(hbp + (size_t)(a[4] >> 16) * 512 + lane * 8);
    int4 hA5 = *(const int4*)(hbp + (size_t)(a[5] >> 16) * 512 + lane * 8);
    int4 hA6 = *(const int4*)(hbp + (size_t)(a[6] >> 16) * 512 + lane * 8);
    int4 hA7 = *(const int4*)(hbp + (size_t)(a[7] >> 16) * 512 + lane * 8);
    int4 hB0 = *(const int4*)(hbp + (size_t)(b[0] >> 16) * 512 + lane * 8);
    int4 hB1 = *(const int4*)(hbp + (size_t)(b[1] >> 16) * 512 + lane * 8);
    int4 hB2 = *(const int4*)(hbp + (size_t)(b[2] >> 16) * 512 + lane * 8);
    int4 hB3 = *(const int4*)(hbp + (size_t)(b[3] >> 16) * 512 + lane * 8);
    int4 hB4 = *(const int4*)(hbp + (size_t)(b[4] >> 16) * 512 + lane * 8);
    int4 hB5 = *(const int4*)(hbp + (size_t)(b[5] >> 16) * 512 + lane * 8);
    int4 hB6 = *(const int4*)(hbp + (size_t)(b[6] >> 16) * 512 + lane * 8);
    int4 hB7 = *(const int4*)(hbp + (size_t)(b[7] >> 16) * 512 + lane * 8);
    union { unsigned int i; float f; } wv;
    wv.i = a[0] << 16; fma8(aA, hA0, wv.f);
    wv.i = a[1] << 16; fma8(aA, hA1, wv.f);
    wv.i = a[2] << 16; fma8(aA, hA2, wv.f);
    wv.i = a[3] << 16; fma8(aA, hA3, wv.f);
    wv.i = a[4] << 16; fma8(aA, hA4, wv.f);
    wv.i = a[5] << 16; fma8(aA, hA5, wv.f);
    wv.i = a[6] << 16; fma8(aA, hA6, wv.f);
    wv.i = a[7] << 16; fma8(aA, hA7, wv.f);
    wv.i = b[0] << 16; fma8(aB, hB0, wv.f);
    wv.i = b[1] << 16; fma8(aB, hB1, wv.f);
    wv.i = b[2] << 16; fma8(aB, hB2, wv.f);
    wv.i = b[3] << 16; fma8(aB, hB3, wv.f);
    wv.i = b[4] << 16; fma8(aB, hB4, wv.f);
    wv.i = b[5] << 16; fma8(aB, hB5, wv.f);
    wv.i = b[6] << 16; fma8(aB, hB6, wv.f);
    wv.i = b[7] << 16; fma8(aB, hB7, wv.f);
}

__global__ __launch_bounds__(256, 3) void gather_kernel(
    const ushort_t* __restrict__ hb, const int* __restrict__ counts,
    const unsigned int* __restrict__ csr, float* __restrict__ out,
    int N, int nc)
{
    const int w = threadIdx.x >> 6;
    const int lane = threadIdx.x & 63;
    const int n0 = (blockIdx.x * 4 + w) * 4;   // wave owns nodes n0..n0+3
    if (n0 >= N) return;
    const int l2 = lane & 31;

    float acc[4][8] = {};

    for (int c = 0; c < nc; ++c) {
        int cq[4];
        unsigned int mq[4];
#pragma unroll
        for (int q = 0; q < 4; ++q) {
            int n = n0 + q;
            bool ok = (n < N);
            int idx = (ok ? n : n0) * nc + c;
            int cv = counts[idx];
            cq[q] = ok ? (cv > CAPC ? CAPC : cv) : 0;
            mq[q] = csr[((size_t)idx << 5) + l2];
        }
        // pair (0,1): interleaved dual bursts -> 16 loads in flight
        {
            int jA = 0, jB = 0;
            while (jA < cq[0] && jB < cq[1]) {
                dual8(hb, mq[0], jA, cq[0], acc[0],
                          mq[1], jB, cq[1], acc[1], lane);
                jA += 8; jB += 8;
            }
            while (jA < cq[0]) { burst8(hb, mq[0], jA, cq[0], lane, acc[0]); jA += 8; }
            while (jB < cq[1]) { burst8(hb, mq[1], jB, cq[1], lane, acc[1]); jB += 8; }
        }
        // pair (2,3)
        {
            int jA = 0, jB = 0;
            while (jA < cq[2] && jB < cq[3]) {
                dual8(hb, mq[2], jA, cq[2], acc[2],
                          mq[3], jB, cq[3], acc[3], lane);
                jA += 8; jB += 8;
            }
            while (jA < cq[2]) { burst8(hb, mq[2], jA, cq[2], lane, acc[2]); jA += 8; }
            while (jB < cq[3]) { burst8(hb, mq[3], jB, cq[3], lane, acc[3]); jB += 8; }
        }
    }

    const size_t bstride = (size_t)N * DOUT;
#pragma unroll
    for (int q = 0; q < 4; ++q) {
        int n = n0 + q;
        if (n < N) {
            float* op = out + (size_t)n * DOUT + lane * 2;
#pragma unroll
            for (int b = 0; b < 4; ++b) {
                float2 v; v.x = acc[q][b]; v.y = acc[q][4 + b];
                *(float2*)(op + b * bstride) = v;
            }
        }
    }
}

// ---------------------------------------------------------------------------
extern "C" void kernel_launch(void* const* d_in, const int* in_sizes, int n_in,
                              void* d_out, int out_size, void* d_ws, size_t ws_size,
                              hipStream_t stream)
{
    const float* x     = (const float*)d_in[0];
    const int*   ei    = (const int*)d_in[1];
    const float* norm  = (const float*)d_in[2];
    const float* W_w   = (const float*)d_in[3];
    const float* W_b   = (const float*)d_in[4];
    const float* gamma = (const float*)d_in[5];
    const float* beta  = (const float*)d_in[6];
    const float* mean  = (const float*)d_in[7];
    const float* var   = (const float*)d_in[8];
    float* out = (float*)d_out;

    const int N = in_sizes[5];             // 10000
    const int E = in_sizes[2];             // 320000
    const int nc = (N + (1 << CHUNK_SHIFT) - 1) >> CHUNK_SHIFT;   // 5 chunks

    // Workspace layout (16B-aligned segments)
    ushort_t* hb      = (ushort_t*)d_ws;                  // N*512 bf16 = 10.24 MB
    uint4* wb         = (uint4*)(hb + (size_t)N * 512);   // 2048 uint4 = 32 KB
    int* counts       = (int*)(wb + 2048);                // N*nc ints = 200 KB
    unsigned int* csr = (unsigned int*)(counts + (size_t)N * nc);  // N*nc*32 u32 = 6.4 MB

    int prep_blocks = (N * nc + 255) / 256;   // 196 (covers 2048 W-tuples too)
    prep_kernel<<<prep_blocks, 256, 0, stream>>>(W_w, wb, counts, N * nc);

    int gemm_blocks = N / 16;              // 625, exact
    gemm_bn_gelu_fill<<<gemm_blocks, 256, 0, stream>>>(
        x, wb, W_b, gamma, beta, mean, var, hb, ei, norm, counts, csr, N, E, nc);

    int gather_blocks = (N + 15) / 16;     // 625: 4 waves x 4 nodes per block
    gather_kernel<<<gather_blocks, 256, 0, stream>>>(hb, counts, csr, out, N, nc);
}